// Round 6
// baseline (3770.758 us; speedup 1.0000x reference)
//
#include <hip/hip_runtime.h>
#include <cstdint>

// LSTM persistent kernel for MI355X (gfx950), round 6.
// B=256, T=1024, I=128, H=256, O=128. All inputs/outputs fp32.
//
// R6 = proven R3 substrate (static grouping, agent-scope RELAXED atomics for
// the h exchange -- no fences, no risky asm) + the two structural fixes the
// R3 counters motivated:
//  1. x prefetch at distance 2, issued AFTER the poll: the poll's vmcnt(0)
//     no longer drains a just-issued HBM demand load (~900 cy/step saved).
//  2. ONE barrier per step: partial[] is parity-double-buffered; the
//     tag-fused h words (tag<<32 | lo_bf16<<16 | hi_bf16) need no flag store
//     and no drain-before-flag. Single clean poll loop (R3 accidentally had
//     two sequential validate loops = an extra serial L3 round trip).
// WAR safety across the 2-parity h buffer: my overwrite of a parity slab
// (tag t+1) is issue-ordered after my poll observed ALL 16 peers' tag t;
// a peer posting tag t has (via its own vmcnt-before-MFMA + barrier order)
// finished consuming the tag t-1 data in that slab. Poison 0xAA never
// matches an expected tag (1..1024) -> no false ready.

#define T_ 1024
#define I_ 128

typedef short s8v __attribute__((ext_vector_type(8)));
typedef float f4v __attribute__((ext_vector_type(4)));
typedef unsigned short u16;
typedef unsigned int   u32;
typedef unsigned long long u64;

__device__ __forceinline__ u16 f2bf(float f) {
  union { float f; u32 u; } v; v.f = f;
  u32 r = v.u + 0x7FFFu + ((v.u >> 16) & 1u);
  return (u16)(r >> 16);
}
__device__ __forceinline__ float bf2f(u16 h) {
  union { u32 u; float f; } v; v.u = ((u32)h) << 16;
  return v.f;
}
__device__ __forceinline__ float sig_(float x)  { return 1.0f / (1.0f + __expf(-x)); }
__device__ __forceinline__ float tanh_(float x) { return 2.0f / (1.0f + __expf(-2.0f * x)) - 1.0f; }

__global__ __launch_bounds__(256, 1) void lstm_persist(
    const float* __restrict__ x, const float* __restrict__ Wih,
    const float* __restrict__ Whh, const float* __restrict__ bih,
    const float* __restrict__ bhh, const float* __restrict__ Wout,
    const float* __restrict__ bout, float* __restrict__ out,
    u64* __restrict__ hbuf)
{
  const int bid  = blockIdx.x;
  // XCD co-location heuristic (perf-only): group members share bid&7.
  const int xcd  = bid & 7;
  const int slot = bid >> 3;
  const int ct   = slot & 15;                 // column tile (0..15)
  const int g    = ((slot >> 4) << 3) | xcd;  // batch group (0..15)
  const int tid  = threadIdx.x;
  const int wave = tid >> 6;
  const int lane = tid & 63;
  const int lm   = lane & 15;
  const int lq   = lane >> 4;

  __shared__ u16   WB[25600];               // 51200 B W staging pool (2 k-halves; Wout later)
  __shared__ u16   xlds[2][2][16][136];     // [parity][hi/lo][m][k+pad]  17408 B
  __shared__ float partial[2][4][4][16][18];// [parity][wave][gate][m][hc] 36864 B

  // ---- stage W slice in two k-halves (concat Wih k<128, Whh k>=128) ----
  auto stageW = [&](int kbeg) {
    for (int it = tid; it < 192 * 64; it += 256) {
      int k = kbeg + (it >> 6);
      int c = it & 63;
      int gcol = (c >> 4) * 256 + ct * 16 + (c & 15);
      float w = (k < 128) ? Wih[k * 1024 + gcol] : Whh[(k - 128) * 1024 + gcol];
      u16 hi = f2bf(w);
      WB[c * 200 + (k - kbeg)]         = hi;
      WB[12800 + c * 200 + (k - kbeg)] = f2bf(w - bf2f(hi));
    }
  };
  // B-frag (16x16x32): lane holds B[k=lq*8+j][n=lm]. wave owns k-tiles {w,w+4,w+8}.
  s8v wfrag[3][4][2];
  stageW(0);
  __syncthreads();
  #pragma unroll
  for (int ki = 0; ki < 3; ki++) {
    const int kt = wave + 4 * ki;
    if (kt < 6)
      #pragma unroll
      for (int gg = 0; gg < 4; gg++)
        #pragma unroll
        for (int p = 0; p < 2; p++)
          wfrag[ki][gg][p] = *(const s8v*)&WB[p * 12800 + (gg * 16 + lm) * 200 + kt * 32 + lq * 8];
  }
  __syncthreads();
  stageW(192);
  __syncthreads();
  #pragma unroll
  for (int ki = 0; ki < 3; ki++) {
    const int kt = wave + 4 * ki;
    if (kt >= 6)
      #pragma unroll
      for (int gg = 0; gg < 4; gg++)
        #pragma unroll
        for (int p = 0; p < 2; p++)
          wfrag[ki][gg][p] = *(const s8v*)&WB[p * 12800 + (gg * 16 + lm) * 200 + (kt * 32 - 192) + lq * 8];
  }

  // cell-update mapping: one thread per (batch m, h-col)
  const int cm  = tid >> 4;
  const int chc = tid & 15;
  float biasv[4];
  #pragma unroll
  for (int gg = 0; gg < 4; gg++) {
    int col = gg * 256 + ct * 16 + chc;
    biasv[gg] = bih[col] + bhh[col];
  }
  float cstate = 0.0f;

  // x mapping: thread loads x[g*16+xr][t][xc0..+7]
  const int xr  = tid >> 4;
  const int xc0 = (tid & 15) * 8;
  const float* xbase = x + (size_t)(g * 16 + xr) * (T_ * I_) + xc0;

  const size_t hpar   = (size_t)16 * 16 * 256;  // parity stride (u64)
  const size_t hgbase = (size_t)g * 16 * 256;

  auto xstore = [&](int par, float4 a, float4 b) {
    float v[8] = {a.x, a.y, a.z, a.w, b.x, b.y, b.z, b.w};
    union { u16 u[8]; s8v s; } hi, lo;
    #pragma unroll
    for (int j = 0; j < 8; j++) {
      u16 h = f2bf(v[j]);
      hi.u[j] = h;
      lo.u[j] = f2bf(v[j] - bf2f(h));
    }
    *(s8v*)&xlds[par][0][xr][xc0] = hi.s;
    *(s8v*)&xlds[par][1][xr][xc0] = lo.s;
  };

  // prologue: x(0) -> xlds[0]; x(1) -> regs
  float4 xa_n, xb_n;
  {
    float4 a = *(const float4*)(xbase + 0);
    float4 b = *(const float4*)(xbase + 4);
    xstore(0, a, b);
  }
  xa_n = *(const float4*)(xbase + I_);
  xb_n = *(const float4*)(xbase + I_ + 4);
  __syncthreads();

  // this lane's h poll/load base: row lm, k = wave*32 + lq*8 (and +128)
  const u64* hb_poll0 = hbuf + hgbase + (size_t)lm * 256 + wave * 32 + lq * 8;

  for (int t = 0; t < T_; t++) {
    const int par = t & 1;
    const int pn  = (t + 1) & 1;

    // stage x(t+1) (regs from last iter) into xlds[pn]
    xstore(pn, xa_n, xb_n);

    f4v acc[4];
    #pragma unroll
    for (int gg = 0; gg < 4; gg++)
      #pragma unroll
      for (int r = 0; r < 4; r++) acc[gg][r] = 0.0f;

    // x-part MFMA (k-tile = wave) from xlds[par] -- runs before the poll
    {
      s8v axh = *(const s8v*)&xlds[par][0][lm][wave * 32 + lq * 8];
      s8v axl = *(const s8v*)&xlds[par][1][lm][wave * 32 + lq * 8];
      #pragma unroll
      for (int gg = 0; gg < 4; gg++) {
        acc[gg] = __builtin_amdgcn_mfma_f32_16x16x32_bf16(axh, wfrag[0][gg][0], acc[gg], 0, 0, 0);
        acc[gg] = __builtin_amdgcn_mfma_f32_16x16x32_bf16(axl, wfrag[0][gg][0], acc[gg], 0, 0, 0);
        acc[gg] = __builtin_amdgcn_mfma_f32_16x16x32_bf16(axh, wfrag[0][gg][1], acc[gg], 0, 0, 0);
      }
    }

    if (t > 0) {
      // fused poll+load: spin until ALL 16 of this lane's h_t words (k and
      // k+128 halves) carry tag t. ONE loop; the validated words are the
      // MFMA operands. Bounded so a protocol bug gives a wrong answer fast
      // instead of a multi-second hang under graph replay.
      const u64* hp = hb_poll0 + (size_t)par * hpar;
      const u32 tt = (u32)t;
      u64 w[16];
      int tries = 0;
      while (true) {
        #pragma unroll
        for (int j = 0; j < 8; j++) {
          w[j]     = __hip_atomic_load(hp + j,       __ATOMIC_RELAXED, __HIP_MEMORY_SCOPE_AGENT);
          w[j + 8] = __hip_atomic_load(hp + 128 + j, __ATOMIC_RELAXED, __HIP_MEMORY_SCOPE_AGENT);
        }
        bool ok = true;
        #pragma unroll
        for (int j = 0; j < 16; j++) ok &= ((u32)(w[j] >> 32) == tt);
        if (__all((int)ok)) break;
        if (++tries > (1 << 14)) break;
      }
      s8v ah1, al1, ah2, al2;
      #pragma unroll
      for (int j = 0; j < 8; j++) {
        u32 d0 = (u32)w[j];
        u32 d1 = (u32)w[j + 8];
        ah1[j] = (short)(u16)d0;  al1[j] = (short)(u16)(d0 >> 16);
        ah2[j] = (short)(u16)d1;  al2[j] = (short)(u16)(d1 >> 16);
      }
      #pragma unroll
      for (int gg = 0; gg < 4; gg++) {
        acc[gg] = __builtin_amdgcn_mfma_f32_16x16x32_bf16(ah1, wfrag[1][gg][0], acc[gg], 0, 0, 0);
        acc[gg] = __builtin_amdgcn_mfma_f32_16x16x32_bf16(al1, wfrag[1][gg][0], acc[gg], 0, 0, 0);
        acc[gg] = __builtin_amdgcn_mfma_f32_16x16x32_bf16(ah1, wfrag[1][gg][1], acc[gg], 0, 0, 0);
        acc[gg] = __builtin_amdgcn_mfma_f32_16x16x32_bf16(ah2, wfrag[2][gg][0], acc[gg], 0, 0, 0);
        acc[gg] = __builtin_amdgcn_mfma_f32_16x16x32_bf16(al2, wfrag[2][gg][0], acc[gg], 0, 0, 0);
        acc[gg] = __builtin_amdgcn_mfma_f32_16x16x32_bf16(ah2, wfrag[2][gg][1], acc[gg], 0, 0, 0);
      }
    }

    // x(t+2) prefetch -- AFTER the poll: its vmcnt wait happens at next
    // iteration's xstore, a full step away (HBM latency hidden).
    {
      const int tn = (t + 2 < T_) ? (t + 2) : (T_ - 1);
      xa_n = *(const float4*)(xbase + (size_t)tn * I_);
      xb_n = *(const float4*)(xbase + (size_t)tn * I_ + 4);
    }

    // per-wave partial gates (C layout: col=lm, row=lq*4+r), parity-buffered
    #pragma unroll
    for (int gg = 0; gg < 4; gg++)
      #pragma unroll
      for (int r = 0; r < 4; r++)
        partial[par][wave][gg][lq * 4 + r][lm] = acc[gg][r];
    __syncthreads();   // the ONLY barrier per step

    // cell update
    float ga = biasv[0], gb = biasv[1], gc = biasv[2], gd = biasv[3];
    #pragma unroll
    for (int w = 0; w < 4; w++) {
      ga += partial[par][w][0][cm][chc];
      gb += partial[par][w][1][cm][chc];
      gc += partial[par][w][2][cm][chc];
      gd += partial[par][w][3][cm][chc];
    }
    float i_t = sig_(ga), f_t = sig_(gb), g_t = tanh_(gc), o_t = sig_(gd);
    cstate = f_t * cstate + i_t * g_t;
    float h = o_t * tanh_(cstate);

    // publish h_{t+1}: one self-validating u64, relaxed agent-scope store
    u16 hhi = f2bf(h);
    u16 hlo = f2bf(h - bf2f(hhi));
    u64 val = ((u64)(u32)(t + 1) << 32) | ((u32)hlo << 16) | (u32)hhi;
    u64* hw = hbuf + (size_t)pn * hpar + hgbase + (size_t)cm * 256 + ct * 16 + chc;
    __hip_atomic_store(hw, val, __ATOMIC_RELAXED, __HIP_MEMORY_SCOPE_AGENT);
  }

  // ---- output projection: out = h_T @ W_out + b_out ----
  // stage W_out cols [ct*8,+8) into WB: [p*4224 + n*264 + k], zero-pad n>=8
  for (int it = tid; it < 16 * 256; it += 256) {
    int n = it >> 8;
    int k = it & 255;
    float w = (n < 8) ? Wout[k * 128 + ct * 8 + n] : 0.0f;
    u16 hi = f2bf(w);
    WB[n * 264 + k]        = hi;
    WB[4224 + n * 264 + k] = f2bf(w - bf2f(hi));
  }
  __syncthreads();

  f4v oacc;
  #pragma unroll
  for (int r = 0; r < 4; r++) oacc[r] = 0.0f;
  #pragma unroll
  for (int ki = 0; ki < 2; ki++) {
    // h_T (tag 1024) lives at parity 0; poll own 8 words per ki
    const int hk = (wave * 2 + ki) * 32 + lq * 8;
    const u64* hp = hbuf + hgbase + (size_t)lm * 256 + hk;
    u64 w[8];
    int tries = 0;
    bool ok;
    do {
      #pragma unroll
      for (int j = 0; j < 8; j++)
        w[j] = __hip_atomic_load(hp + j, __ATOMIC_RELAXED, __HIP_MEMORY_SCOPE_AGENT);
      ok = true;
      #pragma unroll
      for (int j = 0; j < 8; j++) ok &= ((u32)(w[j] >> 32) == (u32)T_);
      if (++tries > (1 << 14)) break;
    } while (!__all((int)ok));
    s8v ahh, ahl;
    #pragma unroll
    for (int j = 0; j < 8; j++) {
      u32 d = (u32)w[j];
      ahh[j] = (short)(u16)d;
      ahl[j] = (short)(u16)(d >> 16);
    }
    s8v bh = *(const s8v*)&WB[lm * 264 + hk];
    s8v bl = *(const s8v*)&WB[4224 + lm * 264 + hk];
    oacc = __builtin_amdgcn_mfma_f32_16x16x32_bf16(ahh, bh, oacc, 0, 0, 0);
    oacc = __builtin_amdgcn_mfma_f32_16x16x32_bf16(ahl, bh, oacc, 0, 0, 0);
    oacc = __builtin_amdgcn_mfma_f32_16x16x32_bf16(ahh, bl, oacc, 0, 0, 0);
  }
  #pragma unroll
  for (int r = 0; r < 4; r++) partial[0][wave][0][lq * 4 + r][lm] = oacc[r];
  __syncthreads();

  if (tid < 128) {
    int m  = tid >> 3;
    int oc = tid & 7;
    float v = bout[ct * 8 + oc];
    #pragma unroll
    for (int w = 0; w < 4; w++) v += partial[0][w][0][m][oc];
    out[(size_t)(g * 16 + m) * 128 + ct * 8 + oc] = v;
  }
}

extern "C" void kernel_launch(void* const* d_in, const int* in_sizes, int n_in,
                              void* d_out, int out_size, void* d_ws, size_t ws_size,
                              hipStream_t stream) {
  const float* x    = (const float*)d_in[0];
  const float* Wih  = (const float*)d_in[1];
  const float* Whh  = (const float*)d_in[2];
  const float* bih  = (const float*)d_in[3];
  const float* bhh  = (const float*)d_in[4];
  const float* Wout = (const float*)d_in[5];
  const float* bout = (const float*)d_in[6];
  float* out = (float*)d_out;

  u64* hbuf = (u64*)d_ws;   // 2 parities * 16 g * 16 * 256 * 8 B = 1 MB

  hipLaunchKernelGGL(lstm_persist, dim3(256), dim3(256), 0, stream,
                     x, Wih, Whh, bih, bhh, Wout, bout, out, hbuf);
}